// Round 1
// baseline (410.212 us; speedup 1.0000x reference)
//
#include <hip/hip_runtime.h>

// LSTM autoencoder, fully fused single kernel. fp32 everywhere (no fp32 MFMA on
// CDNA4 -> VALU). D=64 H=16 L=8 B=4096 T=128.
//
// Layout: 256 blocks x 256 threads = 1024 waves; wave owns 4 batches.
//   GEMM phase   : lane = (grp=batch, li=t within 16-step tile), computes
//                  xg[t][b][64 gates] with uniform-broadcast LDS weight reads.
//   recurrence   : lane = (grp=batch, li=state index j), 4 gates (i,f,g,o row
//                  j,16+j,32+j,48+j), c lane-local, h via 64-float LDS row.
//   xg handoff   : LDS rows r=t*4+b, gate-permuted float4 {i,f,g,o}[j], chunk
//                  index XOR-swizzled by (r&15) to avoid column bank conflicts.
//   decoder      : input gate pre-activation is time-constant (rep broadcast)
//                  -> held in 4 VGPRs; output projection fused (Wo transposed
//                  in LDS [k][d] -> conflict-free b128 reads), writes out
//                  directly (float4, coalesced 256B per batch-group).

constexpr int Dm = 64, Tm = 128;
constexpr int TB = 16;     // timestep tile
constexpr int WAVES = 4;   // waves per block

__device__ __forceinline__ float fexp2(float x) {
#if __has_builtin(__builtin_amdgcn_exp2f)
  return __builtin_amdgcn_exp2f(x);
#else
  return exp2f(x);
#endif
}
__device__ __forceinline__ float frcp(float x) {
#if __has_builtin(__builtin_amdgcn_rcpf)
  return __builtin_amdgcn_rcpf(x);
#else
  return 1.0f / x;
#endif
}
__device__ __forceinline__ float sigm(float x) {
  return frcp(1.0f + fexp2(-1.44269504f * x));
}
__device__ __forceinline__ float tanh_(float x) {
  float xc = fminf(15.0f, fmaxf(-15.0f, x));
  float t = fexp2(2.88539008f * xc);       // e^(2x)
  return (t - 1.0f) * frcp(t + 1.0f);
}
// write->read ordering for intra-wave cross-lane LDS exchange
__device__ __forceinline__ void ldsfence() {
  asm volatile("s_waitcnt lgkmcnt(0)" ::: "memory");
}
__device__ __forceinline__ float dot4(float4 a, float4 b, float acc) {
  return fmaf(a.x, b.x, fmaf(a.y, b.y, fmaf(a.z, b.z, fmaf(a.w, b.w, acc))));
}

__global__ __launch_bounds__(256, 1)
void lstm_ae_kernel(const float* __restrict__ x,
                    const float* __restrict__ eWih, const float* __restrict__ eWhh,
                    const float* __restrict__ eBih, const float* __restrict__ eBhh,
                    const float* __restrict__ Wl,   const float* __restrict__ bl,
                    const float* __restrict__ Wf,   const float* __restrict__ bf,
                    const float* __restrict__ dWih, const float* __restrict__ dWhh,
                    const float* __restrict__ dBih, const float* __restrict__ dBhh,
                    const float* __restrict__ Wo,   const float* __restrict__ bo,
                    float* __restrict__ out)
{
  __shared__ float s_wih[64 * 64];     // enc Wih row-major [g][d]
  __shared__ float s_whhE[64 * 28];    // rows padded to 28 (112B: 16B-aligned, 2-way banks)
  __shared__ float s_whhD[64 * 28];
  __shared__ float s_woT[16 * 64];     // Wo transposed [k][d]
  __shared__ float s_biasE[64];        // eBih + eBhh
  __shared__ float s_xg[WAVES][64 * 64];  // per wave: row r=t*4+b, 16 float4 chunks
  __shared__ float s_h[WAVES][64];        // h broadcast, [b4][16]
  __shared__ float s_lat[WAVES][32];
  __shared__ float s_rep[WAVES][64];

  const int tid = threadIdx.x;
  for (int i = tid; i < 4096; i += 256) s_wih[i] = eWih[i];
  for (int i = tid; i < 1024; i += 256) { int r = i >> 4, k = i & 15; s_whhE[r * 28 + k] = eWhh[i]; }
  for (int i = tid; i < 1024; i += 256) { int r = i >> 4, k = i & 15; s_whhD[r * 28 + k] = dWhh[i]; }
  for (int i = tid; i < 1024; i += 256) { int d = i >> 4, k = i & 15; s_woT[k * 64 + d] = Wo[i]; }
  if (tid < 64) s_biasE[tid] = eBih[tid] + eBhh[tid];
  __syncthreads();   // only block-wide sync; waves independent afterwards

  const int wave = tid >> 6, lane = tid & 63;
  const int grp  = lane >> 4;          // batch within wave
  const int li   = lane & 15;          // t (GEMM phase) or state j (recurrence)
  const int b    = blockIdx.x * 16 + wave * 4 + grp;
  float* xgw = s_xg[wave];
  float* hb  = s_h[wave];

  // ================= encoder =================
  float4 h0 = {0.f, 0.f, 0.f, 0.f}, h1 = h0, h2 = h0, h3 = h0;  // broadcast h[0..15]
  float c = 0.0f;                                               // lane-local c[li]

  for (int tile = 0; tile < Tm / TB; ++tile) {
    // ---- GEMM phase: xg for 16 timesteps of this wave's 4 batches ----
    const float4* xr = (const float4*)(x + ((size_t)b * Tm + tile * TB + li) * Dm);
    float4 xv[16];
#pragma unroll
    for (int dc = 0; dc < 16; ++dc) xv[dc] = xr[dc];
    const int r = li * 4 + grp, key = r & 15;
    float* xrow = xgw + r * 64;
#pragma unroll 1
    for (int gb = 0; gb < 8; ++gb) {          // uniform loop, 8 gates per block
      float acc[8];
#pragma unroll
      for (int gi = 0; gi < 8; ++gi) acc[gi] = s_biasE[gb * 8 + gi];
#pragma unroll
      for (int dc = 0; dc < 16; ++dc) {
        const float4 xd = xv[dc];
#pragma unroll
        for (int gi = 0; gi < 8; ++gi) {
          const float4 w = *(const float4*)&s_wih[((gb * 8 + gi) << 6) + (dc << 2)];
          acc[gi] = dot4(xd, w, acc[gi]);
        }
      }
#pragma unroll
      for (int gi = 0; gi < 8; ++gi) {
        const int g = gb * 8 + gi, j = g & 15, slot = g >> 4;  // slot: 0=i 1=f 2=g 3=o
        xrow[((j ^ key) << 2) + slot] = acc[gi];
      }
    }
    ldsfence();

    // ---- recurrence over the 16 staged steps ----
#pragma unroll 1
    for (int tt = 0; tt < TB; ++tt) {
      const int rr = tt * 4 + grp, kk = rr & 15;
      const float4 g4 = *(const float4*)&xgw[rr * 64 + ((li ^ kk) << 2)];
      float acc[4] = {g4.x, g4.y, g4.z, g4.w};
#pragma unroll
      for (int m = 0; m < 4; ++m) {
        const float* wr = &s_whhE[(m * 16 + li) * 28];
        acc[m] = dot4(h0, *(const float4*)(wr + 0),  acc[m]);
        acc[m] = dot4(h1, *(const float4*)(wr + 4),  acc[m]);
        acc[m] = dot4(h2, *(const float4*)(wr + 8),  acc[m]);
        acc[m] = dot4(h3, *(const float4*)(wr + 12), acc[m]);
      }
      const float iv = sigm(acc[0]), fv = sigm(acc[1]);
      const float gv = tanh_(acc[2]), ov = sigm(acc[3]);
      c = fmaf(fv, c, iv * gv);
      const float hv = ov * tanh_(c);
      hb[grp * 16 + li] = hv;
      ldsfence();
      h0 = *(const float4*)&hb[grp * 16 + 0];
      h1 = *(const float4*)&hb[grp * 16 + 4];
      h2 = *(const float4*)&hb[grp * 16 + 8];
      h3 = *(const float4*)&hb[grp * 16 + 12];
    }
    asm volatile("" ::: "memory");   // xg WAR vs next tile's GEMM writes
  }

  // ================= latent -> rep -> decoder input gates =================
  float dxg[4];
  {
    const int lr = li & 7;
    const float4* wlr = (const float4*)(Wl + lr * 16);
    float lat = bl[lr];
    lat = dot4(h0, wlr[0], lat); lat = dot4(h1, wlr[1], lat);
    lat = dot4(h2, wlr[2], lat); lat = dot4(h3, wlr[3], lat);
    if (li < 8) s_lat[wave][grp * 8 + li] = lat;
    ldsfence();
    const float4 l0 = *(const float4*)&s_lat[wave][grp * 8 + 0];
    const float4 l1 = *(const float4*)&s_lat[wave][grp * 8 + 4];
    const float4* wfr = (const float4*)(Wf + li * 8);
    float rep = bf[li];
    rep = dot4(l0, wfr[0], rep); rep = dot4(l1, wfr[1], rep);
    s_rep[wave][grp * 16 + li] = rep;
    ldsfence();
    const float4 r0 = *(const float4*)&s_rep[wave][grp * 16 + 0];
    const float4 r1 = *(const float4*)&s_rep[wave][grp * 16 + 4];
    const float4 r2 = *(const float4*)&s_rep[wave][grp * 16 + 8];
    const float4 r3 = *(const float4*)&s_rep[wave][grp * 16 + 12];
#pragma unroll
    for (int m = 0; m < 4; ++m) {
      const int g = m * 16 + li;
      const float4* wr = (const float4*)(dWih + g * 16);
      float a = dBih[g] + dBhh[g];
      a = dot4(r0, wr[0], a); a = dot4(r1, wr[1], a);
      a = dot4(r2, wr[2], a); a = dot4(r3, wr[3], a);
      dxg[m] = a;
    }
  }

  // ================= decoder + fused output projection =================
  c = 0.0f;
  h0 = h1 = h2 = h3 = make_float4(0.f, 0.f, 0.f, 0.f);
  const float4 bo4 = *(const float4*)(bo + li * 4);
  float* op = out + (size_t)b * Tm * Dm + li * 4;
#pragma unroll 1
  for (int t = 0; t < Tm; ++t) {
    float acc[4] = {dxg[0], dxg[1], dxg[2], dxg[3]};
#pragma unroll
    for (int m = 0; m < 4; ++m) {
      const float* wr = &s_whhD[(m * 16 + li) * 28];
      acc[m] = dot4(h0, *(const float4*)(wr + 0),  acc[m]);
      acc[m] = dot4(h1, *(const float4*)(wr + 4),  acc[m]);
      acc[m] = dot4(h2, *(const float4*)(wr + 8),  acc[m]);
      acc[m] = dot4(h3, *(const float4*)(wr + 12), acc[m]);
    }
    const float iv = sigm(acc[0]), fv = sigm(acc[1]);
    const float gv = tanh_(acc[2]), ov = sigm(acc[3]);
    c = fmaf(fv, c, iv * gv);
    const float hv = ov * tanh_(c);
    hb[grp * 16 + li] = hv;
    ldsfence();
    h0 = *(const float4*)&hb[grp * 16 + 0];
    h1 = *(const float4*)&hb[grp * 16 + 4];
    h2 = *(const float4*)&hb[grp * 16 + 8];
    h3 = *(const float4*)&hb[grp * 16 + 12];

    // out[b][t][4li..4li+3] = h_new . WoT + bo
    const float hs[16] = {h0.x, h0.y, h0.z, h0.w, h1.x, h1.y, h1.z, h1.w,
                          h2.x, h2.y, h2.z, h2.w, h3.x, h3.y, h3.z, h3.w};
    float4 oa = bo4;
#pragma unroll
    for (int k = 0; k < 16; ++k) {
      const float4 wt = *(const float4*)&s_woT[k * 64 + (li << 2)];
      oa.x = fmaf(hs[k], wt.x, oa.x);
      oa.y = fmaf(hs[k], wt.y, oa.y);
      oa.z = fmaf(hs[k], wt.z, oa.z);
      oa.w = fmaf(hs[k], wt.w, oa.w);
    }
    *(float4*)op = oa;
    op += Dm;
  }
}

extern "C" void kernel_launch(void* const* d_in, const int* in_sizes, int n_in,
                              void* d_out, int out_size, void* d_ws, size_t ws_size,
                              hipStream_t stream) {
  const float* x    = (const float*)d_in[0];
  const float* eWih = (const float*)d_in[1];
  const float* eWhh = (const float*)d_in[2];
  const float* eBih = (const float*)d_in[3];
  const float* eBhh = (const float*)d_in[4];
  const float* Wl   = (const float*)d_in[5];
  const float* bl   = (const float*)d_in[6];
  const float* Wf   = (const float*)d_in[7];
  const float* bf   = (const float*)d_in[8];
  const float* dWih = (const float*)d_in[9];
  const float* dWhh = (const float*)d_in[10];
  const float* dBih = (const float*)d_in[11];
  const float* dBhh = (const float*)d_in[12];
  const float* Wo   = (const float*)d_in[13];
  const float* bo   = (const float*)d_in[14];

  dim3 grid(256), block(256);
  hipLaunchKernelGGL(lstm_ae_kernel, grid, block, 0, stream,
                     x, eWih, eWhh, eBih, eBhh, Wl, bl, Wf, bf,
                     dWih, dWhh, dBih, dBhh, Wo, bo, (float*)d_out);
}

// Round 2
// 358.974 us; speedup vs baseline: 1.1427x; 1.1427x over previous
//
#include <hip/hip_runtime.h>

// LSTM autoencoder, fused, fp32 (no fp32 MFMA on CDNA4 -> VALU).
// D=64 H=16 L=8 B=4096 T=128.
//
// Round-2 restructure: 1 batch per wave, lane = gate row g (4 quadrants
// i,f,g,o x 16 states). 1024 blocks x 256 thr = 4096 waves -> 4 blocks/CU,
// 4 waves/SIMD (vs 1 before). All per-gate weights (Whh/dWhh/Wo/dWih rows)
// live in VGPRs; xg tile lives in 16 accumulator VGPRs (no LDS handoff).
// Per-step cross-lane traffic: 64-float gate exchange + 16-float h
// broadcast, both through tiny per-wave LDS rows.

constexpr int Dm = 64, Tm = 128, TB = 16;

__device__ __forceinline__ float fexp2(float x) {
#if __has_builtin(__builtin_amdgcn_exp2f)
  return __builtin_amdgcn_exp2f(x);
#else
  return exp2f(x);
#endif
}
__device__ __forceinline__ float frcp(float x) {
#if __has_builtin(__builtin_amdgcn_rcpf)
  return __builtin_amdgcn_rcpf(x);
#else
  return 1.0f / x;
#endif
}
__device__ __forceinline__ float sigm(float x) {
  return frcp(1.0f + fexp2(-1.44269504f * x));
}
__device__ __forceinline__ float tanh_(float x) {
  float xc = fminf(15.0f, fmaxf(-15.0f, x));
  float t = fexp2(2.88539008f * xc);       // e^(2x)
  return (t - 1.0f) * frcp(t + 1.0f);
}
__device__ __forceinline__ void ldsfence() {
  asm volatile("s_waitcnt lgkmcnt(0)" ::: "memory");
}
__device__ __forceinline__ float dot4(float4 a, float4 b, float acc) {
  return fmaf(a.x, b.x, fmaf(a.y, b.y, fmaf(a.z, b.z, fmaf(a.w, b.w, acc))));
}

__global__ __launch_bounds__(256, 4)
void lstm_ae_kernel(const float* __restrict__ x,
                    const float* __restrict__ eWih, const float* __restrict__ eWhh,
                    const float* __restrict__ eBih, const float* __restrict__ eBhh,
                    const float* __restrict__ Wl,   const float* __restrict__ bl,
                    const float* __restrict__ Wf,   const float* __restrict__ bf,
                    const float* __restrict__ dWih, const float* __restrict__ dWhh,
                    const float* __restrict__ dBih, const float* __restrict__ dBhh,
                    const float* __restrict__ Wo,   const float* __restrict__ bo,
                    float* __restrict__ out)
{
  __shared__ float s_wih[64 * 68];   // enc Wih rows padded to 68 (272B, 16B-aligned)
  __shared__ float s_wl[128];        // Wl [8][16]
  __shared__ float s_wf[128];        // Wf [16][8]
  __shared__ float s_g[4][64];       // per-wave gate exchange
  __shared__ float s_h[4][16];       // per-wave h broadcast

  const int tid = threadIdx.x;
  for (int i = tid; i < 4096; i += 256) s_wih[(i >> 6) * 68 + (i & 63)] = eWih[i];
  if (tid < 128) s_wl[tid] = Wl[tid];
  else s_wf[tid - 128] = Wf[tid - 128];
  __syncthreads();   // only block-wide sync

  const int wave = tid >> 6, lane = tid & 63;
  const int q = lane >> 4, j = lane & 15;
  const int b = blockIdx.x * 4 + wave;

  // encoder per-gate constants in registers
  const float4* wr = (const float4*)(eWhh + lane * 16);
  float4 w0 = wr[0], w1 = wr[1], w2 = wr[2], w3 = wr[3];
  const float biasg = eBih[lane] + eBhh[lane];

  float4 h0 = {0.f, 0.f, 0.f, 0.f}, h1 = h0, h2 = h0, h3 = h0;  // h[0..15], replicated
  float cst = 0.0f;                                              // c[j], replicated per q
  const float* xb = x + (size_t)b * (Tm * Dm);

  // ================= encoder =================
#pragma unroll 1
  for (int tile = 0; tile < Tm / TB; ++tile) {
    // ---- input projection: xg[t][lane] for 16 timesteps, acc in VGPRs ----
    float acc[TB];
#pragma unroll
    for (int t = 0; t < TB; ++t) acc[t] = biasg;
    const float* xt = xb + tile * (TB * Dm);
#pragma unroll 1
    for (int dc = 0; dc < 16; ++dc) {
      const float4 w4 = *(const float4*)&s_wih[lane * 68 + dc * 4];
#pragma unroll
      for (int t = 0; t < TB; ++t) {
        const float4 x4 = *(const float4*)(xt + t * 64 + dc * 4);  // lane-uniform bcast
        acc[t] = dot4(x4, w4, acc[t]);
      }
    }
    // ---- recurrence over the 16 steps (unrolled: acc[] stays in regs) ----
#pragma unroll
    for (int tt = 0; tt < TB; ++tt) {
      float gp = acc[tt];
      gp = dot4(h0, w0, gp); gp = dot4(h1, w1, gp);
      gp = dot4(h2, w2, gp); gp = dot4(h3, w3, gp);
      s_g[wave][lane] = gp;
      ldsfence();
      const float iv = sigm(s_g[wave][j]);
      const float fv = sigm(s_g[wave][16 + j]);
      const float gv = tanh_(s_g[wave][32 + j]);
      const float ov = sigm(s_g[wave][48 + j]);
      cst = fmaf(fv, cst, iv * gv);
      const float hv = ov * tanh_(cst);
      if (q == 0) s_h[wave][j] = hv;
      ldsfence();
      h0 = *(const float4*)&s_h[wave][0];
      h1 = *(const float4*)&s_h[wave][4];
      h2 = *(const float4*)&s_h[wave][8];
      h3 = *(const float4*)&s_h[wave][12];
    }
  }

  // ================= latent -> rep -> decoder input gate (per lane) =================
  float lat[8];
#pragma unroll
  for (int l = 0; l < 8; ++l) {
    const float4* wl4 = (const float4*)&s_wl[l * 16];
    float a = bl[l];
    a = dot4(h0, wl4[0], a); a = dot4(h1, wl4[1], a);
    a = dot4(h2, wl4[2], a); a = dot4(h3, wl4[3], a);
    lat[l] = a;
  }
  const float4 la0 = {lat[0], lat[1], lat[2], lat[3]};
  const float4 la1 = {lat[4], lat[5], lat[6], lat[7]};
  float rep[16];
#pragma unroll
  for (int k = 0; k < 16; ++k) {
    const float4* wf4 = (const float4*)&s_wf[k * 8];
    float a = bf[k];
    a = dot4(la0, wf4[0], a); a = dot4(la1, wf4[1], a);
    rep[k] = a;
  }
  const float4 r0 = {rep[0], rep[1], rep[2], rep[3]};
  const float4 r1 = {rep[4], rep[5], rep[6], rep[7]};
  const float4 r2 = {rep[8], rep[9], rep[10], rep[11]};
  const float4 r3 = {rep[12], rep[13], rep[14], rep[15]};
  const float4* dwr = (const float4*)(dWih + lane * 16);
  float dxg = dBih[lane] + dBhh[lane];
  dxg = dot4(r0, dwr[0], dxg); dxg = dot4(r1, dwr[1], dxg);
  dxg = dot4(r2, dwr[2], dxg); dxg = dot4(r3, dwr[3], dxg);

  // ================= decoder + fused output projection =================
  wr = (const float4*)(dWhh + lane * 16);
  w0 = wr[0]; w1 = wr[1]; w2 = wr[2]; w3 = wr[3];
  const float4* wor = (const float4*)(Wo + lane * 16);
  const float4 o0 = wor[0], o1 = wor[1], o2 = wor[2], o3 = wor[3];
  const float bog = bo[lane];

  h0 = h1 = h2 = h3 = make_float4(0.f, 0.f, 0.f, 0.f);
  cst = 0.0f;
  float* op = out + (size_t)b * (Tm * Dm) + lane;
#pragma unroll 1
  for (int t = 0; t < Tm; ++t) {
    float gp = dxg;
    gp = dot4(h0, w0, gp); gp = dot4(h1, w1, gp);
    gp = dot4(h2, w2, gp); gp = dot4(h3, w3, gp);
    s_g[wave][lane] = gp;
    ldsfence();
    const float iv = sigm(s_g[wave][j]);
    const float fv = sigm(s_g[wave][16 + j]);
    const float gv = tanh_(s_g[wave][32 + j]);
    const float ov = sigm(s_g[wave][48 + j]);
    cst = fmaf(fv, cst, iv * gv);
    const float hv = ov * tanh_(cst);
    if (q == 0) s_h[wave][j] = hv;
    ldsfence();
    h0 = *(const float4*)&s_h[wave][0];
    h1 = *(const float4*)&s_h[wave][4];
    h2 = *(const float4*)&s_h[wave][8];
    h3 = *(const float4*)&s_h[wave][12];

    float oa = bog;
    oa = dot4(h0, o0, oa); oa = dot4(h1, o1, oa);
    oa = dot4(h2, o2, oa); oa = dot4(h3, o3, oa);
    op[t * 64] = oa;   // wave writes 64 consecutive floats
  }
}

extern "C" void kernel_launch(void* const* d_in, const int* in_sizes, int n_in,
                              void* d_out, int out_size, void* d_ws, size_t ws_size,
                              hipStream_t stream) {
  const float* x    = (const float*)d_in[0];
  const float* eWih = (const float*)d_in[1];
  const float* eWhh = (const float*)d_in[2];
  const float* eBih = (const float*)d_in[3];
  const float* eBhh = (const float*)d_in[4];
  const float* Wl   = (const float*)d_in[5];
  const float* bl   = (const float*)d_in[6];
  const float* Wf   = (const float*)d_in[7];
  const float* bf   = (const float*)d_in[8];
  const float* dWih = (const float*)d_in[9];
  const float* dWhh = (const float*)d_in[10];
  const float* dBih = (const float*)d_in[11];
  const float* dBhh = (const float*)d_in[12];
  const float* Wo   = (const float*)d_in[13];
  const float* bo   = (const float*)d_in[14];

  dim3 grid(1024), block(256);
  hipLaunchKernelGGL(lstm_ae_kernel, grid, block, 0, stream,
                     x, eWih, eWhh, eBih, eBhh, Wl, bl, Wf, bf,
                     dWih, dWhh, dBih, dBhh, Wo, bo, (float*)d_out);
}

// Round 4
// 219.206 us; speedup vs baseline: 1.8714x; 1.6376x over previous
//
#include <hip/hip_runtime.h>

// LSTM autoencoder, fused, fp32 (no fp32 MFMA on CDNA4 -> VALU).
// D=64 H=16 L=8 B=4096 T=128.
//
// Mapping: wave = 1 batch, lane = gate row g = q*16+j (q: i,f,g,o; j: state).
// 1024 blocks x 256 thr = 4096 waves = 4 waves/SIMD (work-capped occupancy).
//
// Round-4: round-3 structure with the h-broadcast FENCE RESTORED (round-3's
// absmax 0.11 failure was the unfenced cross-lane s_h exchange — compiler
// may reorder predicated ds_write vs ds_read_b128 without a barrier; the
// round-2-proven pattern is write -> lgkmcnt(0)+memory-clobber -> read).
//  - x tile (16 steps x 64 = 4KB contiguous): 4 coalesced float4 loads
//    issued ONE TILE AHEAD (hidden under previous tile's recurrence),
//    staged to LDS, uniform broadcast reads in the GEMM dc-loop.
//  - gate exchange via 4x __shfl (register-based, no race possible).
//  - decoder hides the shfl wait behind the output projection of the
//    previous h (out[t-1] stored one step deferred).

constexpr int Dm = 64, Tm = 128, TB = 16;

__device__ __forceinline__ float fexp2(float x) {
#if __has_builtin(__builtin_amdgcn_exp2f)
  return __builtin_amdgcn_exp2f(x);
#else
  return exp2f(x);
#endif
}
__device__ __forceinline__ float frcp(float x) {
#if __has_builtin(__builtin_amdgcn_rcpf)
  return __builtin_amdgcn_rcpf(x);
#else
  return 1.0f / x;
#endif
}
__device__ __forceinline__ float sigm(float x) {
  return frcp(1.0f + fexp2(-1.44269504f * x));
}
__device__ __forceinline__ float tanh_(float x) {
  float xc = fminf(15.0f, fmaxf(-15.0f, x));
  float t = fexp2(2.88539008f * xc);       // e^(2x)
  return (t - 1.0f) * frcp(t + 1.0f);
}
// compiler+hw ordering for cross-lane LDS exchange (round-2-proven)
__device__ __forceinline__ void ldsfence() {
  asm volatile("s_waitcnt lgkmcnt(0)" ::: "memory");
}
__device__ __forceinline__ float dot4(float4 a, float4 b, float acc) {
  return fmaf(a.x, b.x, fmaf(a.y, b.y, fmaf(a.z, b.z, fmaf(a.w, b.w, acc))));
}

__global__ __launch_bounds__(256, 4)
void lstm_ae_kernel(const float* __restrict__ x,
                    const float* __restrict__ eWih, const float* __restrict__ eWhh,
                    const float* __restrict__ eBih, const float* __restrict__ eBhh,
                    const float* __restrict__ Wl,   const float* __restrict__ bl,
                    const float* __restrict__ Wf,   const float* __restrict__ bf,
                    const float* __restrict__ dWih, const float* __restrict__ dWhh,
                    const float* __restrict__ dBih, const float* __restrict__ dBhh,
                    const float* __restrict__ Wo,   const float* __restrict__ bo,
                    float* __restrict__ out)
{
  __shared__ float s_wih[64 * 68];    // enc Wih rows padded to 68 floats
  __shared__ float s_x[4][TB * Dm];   // per-wave 4KB x tile
  __shared__ float s_h[4][16];        // per-wave h broadcast
  __shared__ float s_wl[128];         // Wl [8][16]
  __shared__ float s_wf[128];         // Wf [16][8]

  const int tid = threadIdx.x;
  for (int i = tid; i < 4096; i += 256) s_wih[(i >> 6) * 68 + (i & 63)] = eWih[i];
  if (tid < 128) s_wl[tid] = Wl[tid];
  else s_wf[tid - 128] = Wf[tid - 128];
  __syncthreads();   // only block-wide sync

  const int wave = tid >> 6, lane = tid & 63;
  const int q = lane >> 4, j = lane & 15;
  const int b = blockIdx.x * 4 + wave;
  float* sxw = s_x[wave];

  // encoder per-gate constants in registers
  const float4* wr = (const float4*)(eWhh + lane * 16);
  float4 w0 = wr[0], w1 = wr[1], w2 = wr[2], w3 = wr[3];
  const float biasg = eBih[lane] + eBhh[lane];

  float4 h0 = {0.f, 0.f, 0.f, 0.f}, h1 = h0, h2 = h0, h3 = h0;  // full h, replicated
  float cst = 0.0f;                                              // c[j], replicated per q
  const float* xb = x + (size_t)b * (Tm * Dm);

  // prefetch tile 0 (coalesced: 4 x 1KB per wave)
  float4 xs0 = *(const float4*)(xb + 0 * 256 + lane * 4);
  float4 xs1 = *(const float4*)(xb + 1 * 256 + lane * 4);
  float4 xs2 = *(const float4*)(xb + 2 * 256 + lane * 4);
  float4 xs3 = *(const float4*)(xb + 3 * 256 + lane * 4);

  // ================= encoder =================
#pragma unroll 1
  for (int tile = 0; tile < Tm / TB; ++tile) {
    // stage prefetched tile into LDS (same-wave DS in-order vs GEMM reads)
    *(float4*)&sxw[0 * 256 + lane * 4] = xs0;
    *(float4*)&sxw[1 * 256 + lane * 4] = xs1;
    *(float4*)&sxw[2 * 256 + lane * 4] = xs2;
    *(float4*)&sxw[3 * 256 + lane * 4] = xs3;
    ldsfence();   // writes visible before uniform reads below

    // ---- input projection: xg[t][lane] for 16 timesteps, acc in VGPRs ----
    float acc[TB];
#pragma unroll
    for (int t = 0; t < TB; ++t) acc[t] = biasg;
#pragma unroll 2
    for (int dc = 0; dc < 16; ++dc) {
      const float4 w4 = *(const float4*)&s_wih[lane * 68 + dc * 4];
#pragma unroll
      for (int t = 0; t < TB; ++t) {
        const float4 x4 = *(const float4*)&sxw[t * 64 + dc * 4];  // uniform bcast
        acc[t] = dot4(x4, w4, acc[t]);
      }
    }

    // issue next tile's loads; latency hides under the 16 recurrence steps
    if (tile < Tm / TB - 1) {
      const float* xt = xb + (tile + 1) * (TB * Dm);
      xs0 = *(const float4*)(xt + 0 * 256 + lane * 4);
      xs1 = *(const float4*)(xt + 1 * 256 + lane * 4);
      xs2 = *(const float4*)(xt + 2 * 256 + lane * 4);
      xs3 = *(const float4*)(xt + 3 * 256 + lane * 4);
    }

    // ---- recurrence over the 16 staged steps ----
#pragma unroll
    for (int tt = 0; tt < TB; ++tt) {
      float gp = acc[tt];
      gp = dot4(h0, w0, gp); gp = dot4(h1, w1, gp);
      gp = dot4(h2, w2, gp); gp = dot4(h3, w3, gp);
      const float a0 = __shfl(gp, j);
      const float a1 = __shfl(gp, 16 + j);
      const float a2 = __shfl(gp, 32 + j);
      const float a3 = __shfl(gp, 48 + j);
      const float iv = sigm(a0), fv = sigm(a1);
      const float gv = tanh_(a2), ov = sigm(a3);
      cst = fmaf(fv, cst, iv * gv);
      const float hv = ov * tanh_(cst);
      if (q == 0) s_h[wave][j] = hv;
      ldsfence();   // h write -> broadcast read ordering
      h0 = *(const float4*)&s_h[wave][0];
      h1 = *(const float4*)&s_h[wave][4];
      h2 = *(const float4*)&s_h[wave][8];
      h3 = *(const float4*)&s_h[wave][12];
    }
  }

  // ================= latent -> rep -> decoder input gate (per lane) =================
  float lat[8];
#pragma unroll
  for (int l = 0; l < 8; ++l) {
    const float4* wl4 = (const float4*)&s_wl[l * 16];
    float a = bl[l];
    a = dot4(h0, wl4[0], a); a = dot4(h1, wl4[1], a);
    a = dot4(h2, wl4[2], a); a = dot4(h3, wl4[3], a);
    lat[l] = a;
  }
  const float4 la0 = {lat[0], lat[1], lat[2], lat[3]};
  const float4 la1 = {lat[4], lat[5], lat[6], lat[7]};
  float rep[16];
#pragma unroll
  for (int k = 0; k < 16; ++k) {
    const float4* wf4 = (const float4*)&s_wf[k * 8];
    float a = bf[k];
    a = dot4(la0, wf4[0], a); a = dot4(la1, wf4[1], a);
    rep[k] = a;
  }
  const float4 r0 = {rep[0], rep[1], rep[2], rep[3]};
  const float4 r1 = {rep[4], rep[5], rep[6], rep[7]};
  const float4 r2 = {rep[8], rep[9], rep[10], rep[11]};
  const float4 r3 = {rep[12], rep[13], rep[14], rep[15]};
  const float4* dwr = (const float4*)(dWih + lane * 16);
  float dxg = dBih[lane] + dBhh[lane];
  dxg = dot4(r0, dwr[0], dxg); dxg = dot4(r1, dwr[1], dxg);
  dxg = dot4(r2, dwr[2], dxg); dxg = dot4(r3, dwr[3], dxg);

  // ================= decoder + fused output projection =================
  wr = (const float4*)(dWhh + lane * 16);
  w0 = wr[0]; w1 = wr[1]; w2 = wr[2]; w3 = wr[3];
  const float4* wor = (const float4*)(Wo + lane * 16);
  const float4 o0 = wor[0], o1 = wor[1], o2 = wor[2], o3 = wor[3];
  const float bog = bo[lane];

  h0 = h1 = h2 = h3 = make_float4(0.f, 0.f, 0.f, 0.f);
  cst = 0.0f;
  float* op = out + (size_t)b * (Tm * Dm) + lane;
#pragma unroll 1
  for (int t = 0; t < Tm; ++t) {
    float gp = dxg;
    gp = dot4(h0, w0, gp); gp = dot4(h1, w1, gp);
    gp = dot4(h2, w2, gp); gp = dot4(h3, w3, gp);
    const float a0 = __shfl(gp, j);
    const float a1 = __shfl(gp, 16 + j);
    const float a2 = __shfl(gp, 32 + j);
    const float a3 = __shfl(gp, 48 + j);
    // independent of the shfl results: project PREVIOUS h -> out[t-1]
    float oa = bog;
    oa = dot4(h0, o0, oa); oa = dot4(h1, o1, oa);
    oa = dot4(h2, o2, oa); oa = dot4(h3, o3, oa);
    if (t) op[(t - 1) * 64] = oa;
    const float iv = sigm(a0), fv = sigm(a1);
    const float gv = tanh_(a2), ov = sigm(a3);
    cst = fmaf(fv, cst, iv * gv);
    const float hv = ov * tanh_(cst);
    if (q == 0) s_h[wave][j] = hv;
    ldsfence();   // h write -> broadcast read ordering
    h0 = *(const float4*)&s_h[wave][0];
    h1 = *(const float4*)&s_h[wave][4];
    h2 = *(const float4*)&s_h[wave][8];
    h3 = *(const float4*)&s_h[wave][12];
  }
  // final output row
  float oa = bog;
  oa = dot4(h0, o0, oa); oa = dot4(h1, o1, oa);
  oa = dot4(h2, o2, oa); oa = dot4(h3, o3, oa);
  op[(Tm - 1) * 64] = oa;
}

extern "C" void kernel_launch(void* const* d_in, const int* in_sizes, int n_in,
                              void* d_out, int out_size, void* d_ws, size_t ws_size,
                              hipStream_t stream) {
  const float* x    = (const float*)d_in[0];
  const float* eWih = (const float*)d_in[1];
  const float* eWhh = (const float*)d_in[2];
  const float* eBih = (const float*)d_in[3];
  const float* eBhh = (const float*)d_in[4];
  const float* Wl   = (const float*)d_in[5];
  const float* bl   = (const float*)d_in[6];
  const float* Wf   = (const float*)d_in[7];
  const float* bf   = (const float*)d_in[8];
  const float* dWih = (const float*)d_in[9];
  const float* dWhh = (const float*)d_in[10];
  const float* dBih = (const float*)d_in[11];
  const float* dBhh = (const float*)d_in[12];
  const float* Wo   = (const float*)d_in[13];
  const float* bo   = (const float*)d_in[14];

  dim3 grid(1024), block(256);
  hipLaunchKernelGGL(lstm_ae_kernel, grid, block, 0, stream,
                     x, eWih, eWhh, eBih, eBhh, Wl, bl, Wf, bf,
                     dWih, dWhh, dBih, dBhh, Wo, bo, (float*)d_out);
}

// Round 5
// 201.180 us; speedup vs baseline: 2.0390x; 1.0896x over previous
//
#include <hip/hip_runtime.h>

// LSTM autoencoder, fused, fp32 recurrence (no fp32 MFMA on CDNA4 -> VALU).
// D=64 H=16 L=8 B=4096 T=128.
//
// Mapping: wave = 1 batch, lane = gate row g = q*16+j (q: i,f,g,o; j: state).
// 1024 blocks x 256 thr = 4096 waves = 4 waves/SIMD (work-capped occupancy).
//
// Round-5 (on passing round-4): cut recurrence VALU/transcendental count.
//  - ACTIVATE-THEN-EXCHANGE: each lane applies its own gate's activation
//    (branch-free unified sigmoid/tanh: t=exp2(s*x), av=(qg*t+cm)*rcp(t+1))
//    then 4x shfl exchanges activated values. 10 trans/step -> 4.
//  - gate/output dot products split into 2 independent FMA chains.
//  - unchanged: one-tile-ahead coalesced x prefetch -> LDS staging, fenced
//    h broadcast (round-3 failure proved the fence is required), deferred
//    decoder output store hiding the shfl wait.

constexpr int Dm = 64, Tm = 128, TB = 16;

__device__ __forceinline__ float fexp2(float x) {
#if __has_builtin(__builtin_amdgcn_exp2f)
  return __builtin_amdgcn_exp2f(x);
#else
  return exp2f(x);
#endif
}
__device__ __forceinline__ float frcp(float x) {
#if __has_builtin(__builtin_amdgcn_rcpf)
  return __builtin_amdgcn_rcpf(x);
#else
  return 1.0f / x;
#endif
}
__device__ __forceinline__ float tanh_(float x) {
  float xc = fminf(15.0f, fmaxf(-15.0f, x));
  float t = fexp2(2.88539008f * xc);       // e^(2x)
  return (t - 1.0f) * frcp(t + 1.0f);
}
// compiler+hw ordering for cross-lane LDS exchange (round-2/4-proven)
__device__ __forceinline__ void ldsfence() {
  asm volatile("s_waitcnt lgkmcnt(0)" ::: "memory");
}
__device__ __forceinline__ float dot4(float4 a, float4 b, float acc) {
  return fmaf(a.x, b.x, fmaf(a.y, b.y, fmaf(a.z, b.z, fmaf(a.w, b.w, acc))));
}

__global__ __launch_bounds__(256, 4)
void lstm_ae_kernel(const float* __restrict__ x,
                    const float* __restrict__ eWih, const float* __restrict__ eWhh,
                    const float* __restrict__ eBih, const float* __restrict__ eBhh,
                    const float* __restrict__ Wl,   const float* __restrict__ bl,
                    const float* __restrict__ Wf,   const float* __restrict__ bf,
                    const float* __restrict__ dWih, const float* __restrict__ dWhh,
                    const float* __restrict__ dBih, const float* __restrict__ dBhh,
                    const float* __restrict__ Wo,   const float* __restrict__ bo,
                    float* __restrict__ out)
{
  __shared__ float s_wih[64 * 68];    // enc Wih rows padded to 68 floats
  __shared__ float s_x[4][TB * Dm];   // per-wave 4KB x tile
  __shared__ float s_h[4][16];        // per-wave h broadcast
  __shared__ float s_wl[128];         // Wl [8][16]
  __shared__ float s_wf[128];         // Wf [16][8]

  const int tid = threadIdx.x;
  for (int i = tid; i < 4096; i += 256) s_wih[(i >> 6) * 68 + (i & 63)] = eWih[i];
  if (tid < 128) s_wl[tid] = Wl[tid];
  else s_wf[tid - 128] = Wf[tid - 128];
  __syncthreads();   // only block-wide sync

  const int wave = tid >> 6, lane = tid & 63;
  const int q = lane >> 4, j = lane & 15;
  const int b = blockIdx.x * 4 + wave;
  float* sxw = s_x[wave];

  // branch-free unified activation constants for THIS lane's gate:
  //   q==2 (g-gate, tanh): t=exp2(2/ln2 * x), av=(t-1)*rcp(t+1)
  //   else  (sigmoid)    : t=exp2(-1/ln2 * x), av= 1   *rcp(t+1)
  const float sAct = (q == 2) ? 2.88539008f : -1.44269504f;
  const float qgF  = (q == 2) ? 1.0f : 0.0f;   // num = qgF*t + cmF
  const float cmF  = (q == 2) ? -1.0f : 1.0f;

  // encoder per-gate constants in registers
  const float4* wr = (const float4*)(eWhh + lane * 16);
  float4 w0 = wr[0], w1 = wr[1], w2 = wr[2], w3 = wr[3];
  const float biasg = eBih[lane] + eBhh[lane];

  float4 h0 = {0.f, 0.f, 0.f, 0.f}, h1 = h0, h2 = h0, h3 = h0;  // full h, replicated
  float cst = 0.0f;                                              // c[j], replicated per q
  const float* xb = x + (size_t)b * (Tm * Dm);

  // prefetch tile 0 (coalesced: 4 x 1KB per wave)
  float4 xs0 = *(const float4*)(xb + 0 * 256 + lane * 4);
  float4 xs1 = *(const float4*)(xb + 1 * 256 + lane * 4);
  float4 xs2 = *(const float4*)(xb + 2 * 256 + lane * 4);
  float4 xs3 = *(const float4*)(xb + 3 * 256 + lane * 4);

  // ================= encoder =================
#pragma unroll 1
  for (int tile = 0; tile < Tm / TB; ++tile) {
    // stage prefetched tile into LDS
    *(float4*)&sxw[0 * 256 + lane * 4] = xs0;
    *(float4*)&sxw[1 * 256 + lane * 4] = xs1;
    *(float4*)&sxw[2 * 256 + lane * 4] = xs2;
    *(float4*)&sxw[3 * 256 + lane * 4] = xs3;
    ldsfence();   // writes visible before uniform reads below

    // ---- input projection: xg[t][lane] for 16 timesteps, acc in VGPRs ----
    float acc[TB];
#pragma unroll
    for (int t = 0; t < TB; ++t) acc[t] = biasg;
#pragma unroll 2
    for (int dc = 0; dc < 16; ++dc) {
      const float4 w4 = *(const float4*)&s_wih[lane * 68 + dc * 4];
#pragma unroll
      for (int t = 0; t < TB; ++t) {
        const float4 x4 = *(const float4*)&sxw[t * 64 + dc * 4];  // uniform bcast
        acc[t] = dot4(x4, w4, acc[t]);
      }
    }

    // issue next tile's loads; latency hides under the 16 recurrence steps
    if (tile < Tm / TB - 1) {
      const float* xt = xb + (tile + 1) * (TB * Dm);
      xs0 = *(const float4*)(xt + 0 * 256 + lane * 4);
      xs1 = *(const float4*)(xt + 1 * 256 + lane * 4);
      xs2 = *(const float4*)(xt + 2 * 256 + lane * 4);
      xs3 = *(const float4*)(xt + 3 * 256 + lane * 4);
    }

    // ---- recurrence over the 16 staged steps ----
#pragma unroll
    for (int tt = 0; tt < TB; ++tt) {
      float e0 = dot4(h0, w0, acc[tt]);
      float e1 = dot4(h1, w1, 0.0f);
      e0 = dot4(h2, w2, e0);
      e1 = dot4(h3, w3, e1);
      const float gp = e0 + e1;
      // per-lane activation of OWN gate, then exchange activated values
      const float xc = fminf(15.0f, fmaxf(-15.0f, gp));
      const float t_ = fexp2(sAct * xc);
      const float av = fmaf(qgF, t_, cmF) * frcp(t_ + 1.0f);
      const float iv = __shfl(av, j);
      const float fv = __shfl(av, 16 + j);
      const float gv = __shfl(av, 32 + j);
      const float ov = __shfl(av, 48 + j);
      cst = fmaf(fv, cst, iv * gv);
      const float hv = ov * tanh_(cst);
      if (q == 0) s_h[wave][j] = hv;
      ldsfence();   // h write -> broadcast read ordering
      h0 = *(const float4*)&s_h[wave][0];
      h1 = *(const float4*)&s_h[wave][4];
      h2 = *(const float4*)&s_h[wave][8];
      h3 = *(const float4*)&s_h[wave][12];
    }
  }

  // ================= latent -> rep -> decoder input gate (per lane) =================
  float lat[8];
#pragma unroll
  for (int l = 0; l < 8; ++l) {
    const float4* wl4 = (const float4*)&s_wl[l * 16];
    float a = bl[l];
    a = dot4(h0, wl4[0], a); a = dot4(h1, wl4[1], a);
    a = dot4(h2, wl4[2], a); a = dot4(h3, wl4[3], a);
    lat[l] = a;
  }
  const float4 la0 = {lat[0], lat[1], lat[2], lat[3]};
  const float4 la1 = {lat[4], lat[5], lat[6], lat[7]};
  float rep[16];
#pragma unroll
  for (int k = 0; k < 16; ++k) {
    const float4* wf4 = (const float4*)&s_wf[k * 8];
    float a = bf[k];
    a = dot4(la0, wf4[0], a); a = dot4(la1, wf4[1], a);
    rep[k] = a;
  }
  const float4 r0 = {rep[0], rep[1], rep[2], rep[3]};
  const float4 r1 = {rep[4], rep[5], rep[6], rep[7]};
  const float4 r2 = {rep[8], rep[9], rep[10], rep[11]};
  const float4 r3 = {rep[12], rep[13], rep[14], rep[15]};
  const float4* dwr = (const float4*)(dWih + lane * 16);
  float dxg = dBih[lane] + dBhh[lane];
  dxg = dot4(r0, dwr[0], dxg); dxg = dot4(r1, dwr[1], dxg);
  dxg = dot4(r2, dwr[2], dxg); dxg = dot4(r3, dwr[3], dxg);

  // ================= decoder + fused output projection =================
  wr = (const float4*)(dWhh + lane * 16);
  w0 = wr[0]; w1 = wr[1]; w2 = wr[2]; w3 = wr[3];
  const float4* wor = (const float4*)(Wo + lane * 16);
  const float4 o0 = wor[0], o1 = wor[1], o2 = wor[2], o3 = wor[3];
  const float bog = bo[lane];

  h0 = h1 = h2 = h3 = make_float4(0.f, 0.f, 0.f, 0.f);
  cst = 0.0f;
  float* op = out + (size_t)b * (Tm * Dm) + lane;
#pragma unroll 1
  for (int t = 0; t < Tm; ++t) {
    float e0 = dot4(h0, w0, dxg);
    float e1 = dot4(h1, w1, 0.0f);
    e0 = dot4(h2, w2, e0);
    e1 = dot4(h3, w3, e1);
    const float gp = e0 + e1;
    const float xc = fminf(15.0f, fmaxf(-15.0f, gp));
    const float t_ = fexp2(sAct * xc);
    const float av = fmaf(qgF, t_, cmF) * frcp(t_ + 1.0f);
    const float iv = __shfl(av, j);
    const float fv = __shfl(av, 16 + j);
    const float gv = __shfl(av, 32 + j);
    const float ov = __shfl(av, 48 + j);
    // independent of the shfl results: project PREVIOUS h -> out[t-1]
    float p0 = dot4(h0, o0, bog);
    float p1 = dot4(h1, o1, 0.0f);
    p0 = dot4(h2, o2, p0);
    p1 = dot4(h3, o3, p1);
    if (t) op[(t - 1) * 64] = p0 + p1;
    cst = fmaf(fv, cst, iv * gv);
    const float hv = ov * tanh_(cst);
    if (q == 0) s_h[wave][j] = hv;
    ldsfence();   // h write -> broadcast read ordering
    h0 = *(const float4*)&s_h[wave][0];
    h1 = *(const float4*)&s_h[wave][4];
    h2 = *(const float4*)&s_h[wave][8];
    h3 = *(const float4*)&s_h[wave][12];
  }
  // final output row
  float p0 = dot4(h0, o0, bog);
  float p1 = dot4(h1, o1, 0.0f);
  p0 = dot4(h2, o2, p0);
  p1 = dot4(h3, o3, p1);
  op[(Tm - 1) * 64] = p0 + p1;
}

extern "C" void kernel_launch(void* const* d_in, const int* in_sizes, int n_in,
                              void* d_out, int out_size, void* d_ws, size_t ws_size,
                              hipStream_t stream) {
  const float* x    = (const float*)d_in[0];
  const float* eWih = (const float*)d_in[1];
  const float* eWhh = (const float*)d_in[2];
  const float* eBih = (const float*)d_in[3];
  const float* eBhh = (const float*)d_in[4];
  const float* Wl   = (const float*)d_in[5];
  const float* bl   = (const float*)d_in[6];
  const float* Wf   = (const float*)d_in[7];
  const float* bf   = (const float*)d_in[8];
  const float* dWih = (const float*)d_in[9];
  const float* dWhh = (const float*)d_in[10];
  const float* dBih = (const float*)d_in[11];
  const float* dBhh = (const float*)d_in[12];
  const float* Wo   = (const float*)d_in[13];
  const float* bo   = (const float*)d_in[14];

  dim3 grid(1024), block(256);
  hipLaunchKernelGGL(lstm_ae_kernel, grid, block, 0, stream,
                     x, eWih, eWhh, eBih, eBhh, Wl, bl, Wf, bf,
                     dWih, dWhh, dBih, dBhh, Wo, bo, (float*)d_out);
}